// Round 1
// baseline (685.534 us; speedup 1.0000x reference)
//
#include <hip/hip_runtime.h>
#include <stdint.h>

// Axial attention (H axis), N=8 H=128 W=128 C=512, GROUPS=8, gp=64.
// Pipeline: wconv -> xconv(bf16+permute) -> QKV GEMM (bf16 MFMA) -> attn -> outproj.
// QKV ws layout: [m][1536] bf16, m = (n_local*128 + h); O overwrites Q cols [0,512).

#define QKV_LD 1536

typedef __attribute__((ext_vector_type(4))) float f32x4;
typedef __attribute__((ext_vector_type(8))) short bf16x8;
typedef unsigned short u16;
typedef unsigned int u32;

static __device__ __forceinline__ u16 f2bf(float f){
    union { float f; u32 u; } v; v.f = f;
    u32 r = v.u + 0x7fffu + ((v.u >> 16) & 1u);   // RNE
    return (u16)(r >> 16);
}

static __device__ __forceinline__ void gload16(const void* g, void* l){
    __builtin_amdgcn_global_load_lds((const __attribute__((address_space(1))) void*)g,
                                     (__attribute__((address_space(3))) void*)l, 16, 0, 0);
}

// ---------------- weights fp32 -> bf16 ----------------
__global__ void k_wconv(const float* __restrict__ Wq, const float* __restrict__ Wk,
                        const float* __restrict__ Wv, const float* __restrict__ Wo,
                        u16* __restrict__ Wcat, u16* __restrict__ Wob){
    int e = (blockIdx.x * 256 + threadIdx.x) * 4;
    if (e < 1536*512) {
        int row = e >> 9, col = e & 511;
        const float* s = (row < 512) ? (Wq + row*512)
                        : (row < 1024 ? Wk + (row-512)*512 : Wv + (row-1024)*512);
        float4 v = *(const float4*)(s + col);
        ushort4 o = { f2bf(v.x), f2bf(v.y), f2bf(v.z), f2bf(v.w) };
        *(ushort4*)(Wcat + e) = o;
    } else {
        int e2 = e - 1536*512;
        float4 v = *(const float4*)(Wo + e2);
        ushort4 o = { f2bf(v.x), f2bf(v.y), f2bf(v.z), f2bf(v.w) };
        *(ushort4*)(Wob + e2) = o;
    }
}

// ---------------- x fp32 (N,H,W,C) -> xb bf16 [(n0+nl)*128+h][512] ----------------
__global__ void k_xconv(const float* __restrict__ x, u16* __restrict__ xb, int n0){
    int t = blockIdx.x * 256 + threadIdx.x;
    int ml = t >> 6;                 // chunk-local token row
    int c0 = (t & 63) << 3;          // 8 channels per thread
    int nl = ml >> 7, h = ml & 127;
    int n = n0 + nl, nb = n >> 7, w = n & 127;
    const float* src = x + (size_t)((nb*128 + h)*128 + w) * 512 + c0;
    float4 a = *(const float4*)(src);
    float4 b = *(const float4*)(src + 4);
    uint4 o;
    o.x = (u32)f2bf(a.x) | ((u32)f2bf(a.y) << 16);
    o.y = (u32)f2bf(a.z) | ((u32)f2bf(a.w) << 16);
    o.z = (u32)f2bf(b.x) | ((u32)f2bf(b.y) << 16);
    o.w = (u32)f2bf(b.z) | ((u32)f2bf(b.w) << 16);
    *(uint4*)(xb + (size_t)ml*512 + c0) = o;
}

// ---------------- GEMM: C[MxN] = A[MxK=512] * B^T (B rows are output cols) ----------------
// 128x128 tile, BK=64, 4 waves (2x2 of 64x64), global_load_lds w/ inverse-swizzled source,
// XOR-swizzled ds_read_b128 (byte ^= (row&7)<<4) -> conflict-floor LDS reads.
template<int LDA, bool OUTPROJ>
__global__ __launch_bounds__(256, 2) void k_gemm(const u16* __restrict__ A, const u16* __restrict__ B,
                                                 void* __restrict__ Cout, const float* __restrict__ bias,
                                                 int n0){
    __shared__ char sm[32768];   // As [0,16K), Bs [16K,32K)
    const int tid = threadIdx.x;
    const int wid = tid >> 6, lane = tid & 63, lg = lane >> 4, li = lane & 15;
    const int m0 = blockIdx.x * 128, nn0 = blockIdx.y * 128;
    const int wm = (wid >> 1) * 64, wn = (wid & 1) * 64;

    f32x4 acc[4][4];
    #pragma unroll
    for (int i = 0; i < 4; ++i)
        #pragma unroll
        for (int j = 0; j < 4; ++j)
            acc[i][j] = f32x4{0.f, 0.f, 0.f, 0.f};

    for (int k0 = 0; k0 < 512; k0 += 64) {
        if (k0) __syncthreads();
        #pragma unroll
        for (int it = 0; it < 4; ++it) {
            int gi = it*256 + tid;
            int row = gi >> 3, gs = gi & 7;
            int sw = (gs ^ (row & 7)) << 4;
            gload16((const char*)(A + (size_t)(m0 + row)*LDA + k0) + sw,
                    sm + it*4096 + wid*1024);
            gload16((const char*)(B + (size_t)(nn0 + row)*512 + k0) + sw,
                    sm + 16384 + it*4096 + wid*1024);
        }
        __syncthreads();
        #pragma unroll
        for (int ks = 0; ks < 2; ++ks) {
            bf16x8 af[4], bfr[4];
            #pragma unroll
            for (int t = 0; t < 4; ++t) {
                int ra = wm + t*16 + li;
                af[t]  = *(const bf16x8*)(sm + ra*128 + ((ks*64 + lg*16) ^ ((ra & 7) << 4)));
                int rb = wn + t*16 + li;
                bfr[t] = *(const bf16x8*)(sm + 16384 + rb*128 + ((ks*64 + lg*16) ^ ((rb & 7) << 4)));
            }
            #pragma unroll
            for (int i = 0; i < 4; ++i)
                #pragma unroll
                for (int j = 0; j < 4; ++j)
                    acc[i][j] = __builtin_amdgcn_mfma_f32_16x16x32_bf16(af[i], bfr[j], acc[i][j], 0, 0, 0);
        }
    }

    if (!OUTPROJ) {
        u16* C = (u16*)Cout;
        #pragma unroll
        for (int i = 0; i < 4; ++i)
            #pragma unroll
            for (int j = 0; j < 4; ++j)
                #pragma unroll
                for (int r = 0; r < 4; ++r) {
                    int row = m0 + wm + i*16 + lg*4 + r;
                    int col = nn0 + wn + j*16 + li;
                    C[(size_t)row*QKV_LD + col] = f2bf(acc[i][j][r]);
                }
    } else {
        float* C = (float*)Cout;
        #pragma unroll
        for (int i = 0; i < 4; ++i)
            #pragma unroll
            for (int j = 0; j < 4; ++j)
                #pragma unroll
                for (int r = 0; r < 4; ++r) {
                    int row = m0 + wm + i*16 + lg*4 + r;   // chunk-local token
                    int col = nn0 + wn + j*16 + li;
                    int mg = n0*128 + row;
                    int n = mg >> 7, ii = mg & 127;        // n = nb*128+w, ii = h
                    int nb = n >> 7, w = n & 127;
                    C[(size_t)((nb*128 + ii)*128 + w) * 512 + col] = acc[i][j][r] + bias[col];
                }
    }
}

// ---------------- attention: one block per (n_local, group), 4 waves x 32 rows ----------------
__global__ __launch_bounds__(256, 2) void k_attn(u16* __restrict__ QKV){
    // LDS: [0,16K) Qs swz, [16K,32K) Ks swz; P overlays [0,34816) after S-phase;
    //      Vt [34816, 34816+17408): [c=64][stride 272B] bf16
    __shared__ char sm[52224];
    const int g = blockIdx.x;
    const int nl = blockIdx.y;
    const int tid = threadIdx.x;
    const int wid = tid >> 6, lane = tid & 63, lg = lane >> 4, li = lane & 15;

    u16* Qg = QKV + (size_t)nl*128*QKV_LD + g*64;   // K at +512, V at +1024

    #pragma unroll
    for (int it = 0; it < 4; ++it) {
        int gi = it*256 + tid;
        int row = gi >> 3, gs = gi & 7;
        int sw = (gs ^ (row & 7)) << 4;
        gload16((const char*)(Qg + (size_t)row*QKV_LD) + sw,        sm + it*4096 + wid*1024);
        gload16((const char*)(Qg + 512 + (size_t)row*QKV_LD) + sw,  sm + 16384 + it*4096 + wid*1024);
    }
    {   // V transposed: Vt[c][j]
        int j = tid & 127, ch = tid >> 7;
        const u16* src = Qg + 1024 + (size_t)j*QKV_LD + ch*32;
        char* dst = sm + 34816 + ch*32*272 + j*2;
        #pragma unroll
        for (int cc = 0; cc < 32; ++cc)
            *(u16*)(dst + cc*272) = src[cc];
    }
    __syncthreads();

    const int i0w = wid*32;
    f32x4 s[2][8];
    #pragma unroll
    for (int t = 0; t < 2; ++t)
        #pragma unroll
        for (int tj = 0; tj < 8; ++tj)
            s[t][tj] = f32x4{0.f,0.f,0.f,0.f};

    #pragma unroll
    for (int ks = 0; ks < 2; ++ks) {
        bf16x8 qf[2];
        #pragma unroll
        for (int t = 0; t < 2; ++t) {
            int ra = i0w + t*16 + li;
            qf[t] = *(const bf16x8*)(sm + ra*128 + ((ks*64 + lg*16) ^ ((ra & 7) << 4)));
        }
        #pragma unroll
        for (int tj = 0; tj < 8; ++tj) {
            int rb = tj*16 + li;
            bf16x8 kf = *(const bf16x8*)(sm + 16384 + rb*128 + ((ks*64 + lg*16) ^ ((rb & 7) << 4)));
            #pragma unroll
            for (int t = 0; t < 2; ++t)
                s[t][tj] = __builtin_amdgcn_mfma_f32_16x16x32_bf16(qf[t], kf, s[t][tj], 0, 0, 0);
        }
    }
    __syncthreads();   // Q/K LDS dead -> P overlay is now safe

    // wave-parallel softmax over j (scale 1/8 folded into exp arg)
    char* pb = sm + wid*8704;     // per-wave P [32 rows][272B stride]
    #pragma unroll
    for (int t = 0; t < 2; ++t) {
        #pragma unroll
        for (int r = 0; r < 4; ++r) {
            float mx = -1e30f;
            #pragma unroll
            for (int tj = 0; tj < 8; ++tj) mx = fmaxf(mx, s[t][tj][r]);
            #pragma unroll
            for (int off = 1; off < 16; off <<= 1) mx = fmaxf(mx, __shfl_xor(mx, off, 64));
            float p[8]; float sum = 0.f;
            #pragma unroll
            for (int tj = 0; tj < 8; ++tj) { p[tj] = __expf((s[t][tj][r] - mx)*0.125f); sum += p[tj]; }
            #pragma unroll
            for (int off = 1; off < 16; off <<= 1) sum += __shfl_xor(sum, off, 64);
            float inv = 1.0f / sum;
            int prow = t*16 + lg*4 + r;
            #pragma unroll
            for (int tj = 0; tj < 8; ++tj)
                *(u16*)(pb + prow*272 + (tj*16 + li)*2) = f2bf(p[tj]*inv);
        }
    }

    // O = P @ V
    f32x4 o[2][4];
    #pragma unroll
    for (int t = 0; t < 2; ++t)
        #pragma unroll
        for (int tc = 0; tc < 4; ++tc)
            o[t][tc] = f32x4{0.f,0.f,0.f,0.f};

    #pragma unroll
    for (int ks = 0; ks < 4; ++ks) {
        bf16x8 pf[2];
        #pragma unroll
        for (int t = 0; t < 2; ++t)
            pf[t] = *(const bf16x8*)(pb + (t*16 + li)*272 + (ks*64 + lg*16));
        #pragma unroll
        for (int tc = 0; tc < 4; ++tc) {
            bf16x8 vf = *(const bf16x8*)(sm + 34816 + (tc*16 + li)*272 + (ks*64 + lg*16));
            #pragma unroll
            for (int t = 0; t < 2; ++t)
                o[t][tc] = __builtin_amdgcn_mfma_f32_16x16x32_bf16(pf[t], vf, o[t][tc], 0, 0, 0);
        }
    }

    // O overwrites this block's Q slice (consumed into LDS at block start)
    #pragma unroll
    for (int t = 0; t < 2; ++t)
        #pragma unroll
        for (int tc = 0; tc < 4; ++tc)
            #pragma unroll
            for (int r = 0; r < 4; ++r) {
                int irow = i0w + t*16 + lg*4 + r;
                int col = tc*16 + li;
                Qg[(size_t)irow*QKV_LD + col] = f2bf(o[t][tc][r]);
            }
}

extern "C" void kernel_launch(void* const* d_in, const int* in_sizes, int n_in,
                              void* d_out, int out_size, void* d_ws, size_t ws_size,
                              hipStream_t stream){
    const float* x  = (const float*)d_in[0];
    const float* Wq = (const float*)d_in[1];
    const float* Wk = (const float*)d_in[2];
    const float* Wv = (const float*)d_in[3];
    const float* Wo = (const float*)d_in[4];
    const float* bo = (const float*)d_in[5];

    char* ws = (char*)d_ws;
    u16* Wcat = (u16*)ws;               // 1536*512 bf16
    u16* Wob  = Wcat + 1536*512;        // 512*512 bf16 ; weights end at 2097152 B

    // chunk over the 1024 attention rows to fit ws: per chunk = CN*128*(512+1536)*2 B
    int CN = 1024;
    while (CN > 64 && (size_t)2097152 + (size_t)CN*524288 > ws_size) CN >>= 1;
    u16* xb  = (u16*)(ws + 2097152);
    u16* QKV = xb + (size_t)CN*128*512;

    k_wconv<<<1024, 256, 0, stream>>>(Wq, Wk, Wv, Wo, Wcat, Wob);
    int nch = 1024 / CN;
    for (int ch = 0; ch < nch; ++ch) {
        int n0 = ch * CN;
        k_xconv<<<CN*32, 256, 0, stream>>>(x, xb, n0);
        k_gemm<512,    false><<<dim3(CN, 12), 256, 0, stream>>>(xb, Wcat, QKV, nullptr, 0);
        k_attn<<<dim3(8, CN), 256, 0, stream>>>(QKV);
        k_gemm<QKV_LD, true ><<<dim3(CN, 4),  256, 0, stream>>>(QKV, Wob, d_out, bo, n0);
    }
}

// Round 2
// 663.137 us; speedup vs baseline: 1.0338x; 1.0338x over previous
//
#include <hip/hip_runtime.h>
#include <stdint.h>

// Axial attention (H axis), N=8 H=128 W=128 C=512, GROUPS=8, gp=64.
// Pipeline: wconv -> xconv(bf16+permute) -> QKV GEMM (bf16 MFMA) -> attn -> outproj.
// QKV ws layout: [m][1536] bf16, m = (n_local*128 + h); O overwrites Q cols [0,512).

#define QKV_LD 1536

typedef __attribute__((ext_vector_type(4))) float f32x4;
typedef __attribute__((ext_vector_type(8))) short bf16x8;
typedef unsigned short u16;
typedef unsigned int u32;

static __device__ __forceinline__ u16 f2bf(float f){
    union { float f; u32 u; } v; v.f = f;
    u32 r = v.u + 0x7fffu + ((v.u >> 16) & 1u);   // RNE
    return (u16)(r >> 16);
}

static __device__ __forceinline__ void gload16(const void* g, void* l){
    __builtin_amdgcn_global_load_lds((const __attribute__((address_space(1))) void*)g,
                                     (__attribute__((address_space(3))) void*)l, 16, 0, 0);
}

// ---------------- weights fp32 -> bf16 ----------------
__global__ void k_wconv(const float* __restrict__ Wq, const float* __restrict__ Wk,
                        const float* __restrict__ Wv, const float* __restrict__ Wo,
                        u16* __restrict__ Wcat, u16* __restrict__ Wob){
    int e = (blockIdx.x * 256 + threadIdx.x) * 4;
    if (e < 1536*512) {
        int row = e >> 9, col = e & 511;
        const float* s = (row < 512) ? (Wq + row*512)
                        : (row < 1024 ? Wk + (row-512)*512 : Wv + (row-1024)*512);
        float4 v = *(const float4*)(s + col);
        ushort4 o = { f2bf(v.x), f2bf(v.y), f2bf(v.z), f2bf(v.w) };
        *(ushort4*)(Wcat + e) = o;
    } else {
        int e2 = e - 1536*512;
        float4 v = *(const float4*)(Wo + e2);
        ushort4 o = { f2bf(v.x), f2bf(v.y), f2bf(v.z), f2bf(v.w) };
        *(ushort4*)(Wob + e2) = o;
    }
}

// ---------------- x fp32 (N,H,W,C) -> xb bf16 [(n0+nl)*128+h][512] ----------------
__global__ void k_xconv(const float* __restrict__ x, u16* __restrict__ xb, int n0){
    int t = blockIdx.x * 256 + threadIdx.x;
    int ml = t >> 6;                 // chunk-local token row
    int c0 = (t & 63) << 3;          // 8 channels per thread
    int nl = ml >> 7, h = ml & 127;
    int n = n0 + nl, nb = n >> 7, w = n & 127;
    const float* src = x + (size_t)((nb*128 + h)*128 + w) * 512 + c0;
    float4 a = *(const float4*)(src);
    float4 b = *(const float4*)(src + 4);
    uint4 o;
    o.x = (u32)f2bf(a.x) | ((u32)f2bf(a.y) << 16);
    o.y = (u32)f2bf(a.z) | ((u32)f2bf(a.w) << 16);
    o.z = (u32)f2bf(b.x) | ((u32)f2bf(b.y) << 16);
    o.w = (u32)f2bf(b.z) | ((u32)f2bf(b.w) << 16);
    *(uint4*)(xb + (size_t)ml*512 + c0) = o;
}

// ---------------- GEMM: C[MxN] = A[MxK=512] * B^T (B rows are output cols) ----------------
// 128x128 tile, BK=64, 4 waves (2x2 of 64x64), global_load_lds w/ inverse-swizzled source,
// XOR-swizzled ds_read_b128 (byte ^= (row&7)<<4) -> conflict-floor LDS reads.
// 1-D grid with XCD-chunked mapping: bid%8 = XCD, col-tile fastest within XCD so the
// NCOL blocks sharing one A row-panel are co-resident on one XCD's L2 (kills A re-fetch).
template<int LDA, int NCOL, bool OUTPROJ>
__global__ __launch_bounds__(256, 2) void k_gemm(const u16* __restrict__ A, const u16* __restrict__ B,
                                                 void* __restrict__ Cout, const float* __restrict__ bias,
                                                 int n0, int nrow){
    __shared__ char sm[32768];   // As [0,16K), Bs [16K,32K)
    const int tid = threadIdx.x;
    const int wid = tid >> 6, lane = tid & 63, lg = lane >> 4, li = lane & 15;
    const int bid = blockIdx.x;
    const int xcd = bid & 7, l = bid >> 3;
    const int row_tile = xcd * (nrow >> 3) + l / NCOL;
    const int col_tile = l % NCOL;
    const int m0 = row_tile * 128, nn0 = col_tile * 128;
    const int wm = (wid >> 1) * 64, wn = (wid & 1) * 64;

    f32x4 acc[4][4];
    #pragma unroll
    for (int i = 0; i < 4; ++i)
        #pragma unroll
        for (int j = 0; j < 4; ++j)
            acc[i][j] = f32x4{0.f, 0.f, 0.f, 0.f};

    for (int k0 = 0; k0 < 512; k0 += 64) {
        if (k0) __syncthreads();
        #pragma unroll
        for (int it = 0; it < 4; ++it) {
            int gi = it*256 + tid;
            int row = gi >> 3, gs = gi & 7;
            int sw = (gs ^ (row & 7)) << 4;
            gload16((const char*)(A + (size_t)(m0 + row)*LDA + k0) + sw,
                    sm + it*4096 + wid*1024);
            gload16((const char*)(B + (size_t)(nn0 + row)*512 + k0) + sw,
                    sm + 16384 + it*4096 + wid*1024);
        }
        __syncthreads();
        #pragma unroll
        for (int ks = 0; ks < 2; ++ks) {
            bf16x8 af[4], bfr[4];
            #pragma unroll
            for (int t = 0; t < 4; ++t) {
                int ra = wm + t*16 + li;
                af[t]  = *(const bf16x8*)(sm + ra*128 + ((ks*64 + lg*16) ^ ((ra & 7) << 4)));
                int rb = wn + t*16 + li;
                bfr[t] = *(const bf16x8*)(sm + 16384 + rb*128 + ((ks*64 + lg*16) ^ ((rb & 7) << 4)));
            }
            #pragma unroll
            for (int i = 0; i < 4; ++i)
                #pragma unroll
                for (int j = 0; j < 4; ++j)
                    acc[i][j] = __builtin_amdgcn_mfma_f32_16x16x32_bf16(af[i], bfr[j], acc[i][j], 0, 0, 0);
        }
    }

    if (!OUTPROJ) {
        u16* C = (u16*)Cout;
        #pragma unroll
        for (int i = 0; i < 4; ++i)
            #pragma unroll
            for (int j = 0; j < 4; ++j)
                #pragma unroll
                for (int r = 0; r < 4; ++r) {
                    int row = m0 + wm + i*16 + lg*4 + r;
                    int col = nn0 + wn + j*16 + li;
                    C[(size_t)row*QKV_LD + col] = f2bf(acc[i][j][r]);
                }
    } else {
        float* C = (float*)Cout;
        #pragma unroll
        for (int i = 0; i < 4; ++i)
            #pragma unroll
            for (int j = 0; j < 4; ++j)
                #pragma unroll
                for (int r = 0; r < 4; ++r) {
                    int row = m0 + wm + i*16 + lg*4 + r;   // chunk-local token
                    int col = nn0 + wn + j*16 + li;
                    int mg = n0*128 + row;
                    int n = mg >> 7, ii = mg & 127;        // n = nb*128+w, ii = h
                    int nb = n >> 7, w = n & 127;
                    C[(size_t)((nb*128 + ii)*128 + w) * 512 + col] = acc[i][j][r] + bias[col];
                }
    }
}

// ---------------- attention: one block per (n_local, group), 4 waves x 32 rows ----------------
__global__ __launch_bounds__(256, 2) void k_attn(u16* __restrict__ QKV){
    // LDS: [0,16K) Qs swz, [16K,32K) Ks swz; P overlays [0,34816) after S-phase;
    //      Vt [34816, 34816+17408): [c=64][stride 272B] bf16
    __shared__ char sm[52224];
    const int g = blockIdx.x;
    const int nl = blockIdx.y;
    const int tid = threadIdx.x;
    const int wid = tid >> 6, lane = tid & 63, lg = lane >> 4, li = lane & 15;

    u16* Qg = QKV + (size_t)nl*128*QKV_LD + g*64;   // K at +512, V at +1024

    #pragma unroll
    for (int it = 0; it < 4; ++it) {
        int gi = it*256 + tid;
        int row = gi >> 3, gs = gi & 7;
        int sw = (gs ^ (row & 7)) << 4;
        gload16((const char*)(Qg + (size_t)row*QKV_LD) + sw,        sm + it*4096 + wid*1024);
        gload16((const char*)(Qg + 512 + (size_t)row*QKV_LD) + sw,  sm + 16384 + it*4096 + wid*1024);
    }
    {   // V transposed: Vt[c][j] — vectorized global loads, scalar LDS scatter
        int j = tid & 127, ch = tid >> 7;
        const u16* src = Qg + 1024 + (size_t)j*QKV_LD + ch*32;
        uint4 a0 = *(const uint4*)(src);
        uint4 a1 = *(const uint4*)(src + 8);
        uint4 a2 = *(const uint4*)(src + 16);
        uint4 a3 = *(const uint4*)(src + 24);
        u32 w[16] = {a0.x,a0.y,a0.z,a0.w, a1.x,a1.y,a1.z,a1.w,
                     a2.x,a2.y,a2.z,a2.w, a3.x,a3.y,a3.z,a3.w};
        char* dst = sm + 34816 + ch*32*272 + j*2;
        #pragma unroll
        for (int cc = 0; cc < 32; ++cc) {
            u32 word = w[cc >> 1];
            u16 val = (cc & 1) ? (u16)(word >> 16) : (u16)(word & 0xffffu);
            *(u16*)(dst + cc*272) = val;
        }
    }
    __syncthreads();

    const int i0w = wid*32;
    f32x4 s[2][8];
    #pragma unroll
    for (int t = 0; t < 2; ++t)
        #pragma unroll
        for (int tj = 0; tj < 8; ++tj)
            s[t][tj] = f32x4{0.f,0.f,0.f,0.f};

    #pragma unroll
    for (int ks = 0; ks < 2; ++ks) {
        bf16x8 qf[2];
        #pragma unroll
        for (int t = 0; t < 2; ++t) {
            int ra = i0w + t*16 + li;
            qf[t] = *(const bf16x8*)(sm + ra*128 + ((ks*64 + lg*16) ^ ((ra & 7) << 4)));
        }
        #pragma unroll
        for (int tj = 0; tj < 8; ++tj) {
            int rb = tj*16 + li;
            bf16x8 kf = *(const bf16x8*)(sm + 16384 + rb*128 + ((ks*64 + lg*16) ^ ((rb & 7) << 4)));
            #pragma unroll
            for (int t = 0; t < 2; ++t)
                s[t][tj] = __builtin_amdgcn_mfma_f32_16x16x32_bf16(qf[t], kf, s[t][tj], 0, 0, 0);
        }
    }
    __syncthreads();   // Q/K LDS dead -> P overlay is now safe

    // wave-parallel softmax over j (scale 1/8 folded into exp arg)
    char* pb = sm + wid*8704;     // per-wave P [32 rows][272B stride]
    #pragma unroll
    for (int t = 0; t < 2; ++t) {
        #pragma unroll
        for (int r = 0; r < 4; ++r) {
            float mx = -1e30f;
            #pragma unroll
            for (int tj = 0; tj < 8; ++tj) mx = fmaxf(mx, s[t][tj][r]);
            #pragma unroll
            for (int off = 1; off < 16; off <<= 1) mx = fmaxf(mx, __shfl_xor(mx, off, 64));
            float p[8]; float sum = 0.f;
            #pragma unroll
            for (int tj = 0; tj < 8; ++tj) { p[tj] = __expf((s[t][tj][r] - mx)*0.125f); sum += p[tj]; }
            #pragma unroll
            for (int off = 1; off < 16; off <<= 1) sum += __shfl_xor(sum, off, 64);
            float inv = 1.0f / sum;
            int prow = t*16 + lg*4 + r;
            #pragma unroll
            for (int tj = 0; tj < 8; ++tj)
                *(u16*)(pb + prow*272 + (tj*16 + li)*2) = f2bf(p[tj]*inv);
        }
    }

    // O = P @ V
    f32x4 o[2][4];
    #pragma unroll
    for (int t = 0; t < 2; ++t)
        #pragma unroll
        for (int tc = 0; tc < 4; ++tc)
            o[t][tc] = f32x4{0.f,0.f,0.f,0.f};

    #pragma unroll
    for (int ks = 0; ks < 4; ++ks) {
        bf16x8 pf[2];
        #pragma unroll
        for (int t = 0; t < 2; ++t)
            pf[t] = *(const bf16x8*)(pb + (t*16 + li)*272 + (ks*64 + lg*16));
        #pragma unroll
        for (int tc = 0; tc < 4; ++tc) {
            bf16x8 vf = *(const bf16x8*)(sm + 34816 + (tc*16 + li)*272 + (ks*64 + lg*16));
            #pragma unroll
            for (int t = 0; t < 2; ++t)
                o[t][tc] = __builtin_amdgcn_mfma_f32_16x16x32_bf16(pf[t], vf, o[t][tc], 0, 0, 0);
        }
    }

    // O overwrites this block's Q slice (consumed into LDS at block start)
    #pragma unroll
    for (int t = 0; t < 2; ++t)
        #pragma unroll
        for (int tc = 0; tc < 4; ++tc)
            #pragma unroll
            for (int r = 0; r < 4; ++r) {
                int irow = i0w + t*16 + lg*4 + r;
                int col = tc*16 + li;
                Qg[(size_t)irow*QKV_LD + col] = f2bf(o[t][tc][r]);
            }
}

extern "C" void kernel_launch(void* const* d_in, const int* in_sizes, int n_in,
                              void* d_out, int out_size, void* d_ws, size_t ws_size,
                              hipStream_t stream){
    const float* x  = (const float*)d_in[0];
    const float* Wq = (const float*)d_in[1];
    const float* Wk = (const float*)d_in[2];
    const float* Wv = (const float*)d_in[3];
    const float* Wo = (const float*)d_in[4];
    const float* bo = (const float*)d_in[5];

    char* ws = (char*)d_ws;
    u16* Wcat = (u16*)ws;               // 1536*512 bf16
    u16* Wob  = Wcat + 1536*512;        // 512*512 bf16 ; weights end at 2097152 B

    // chunk over the 1024 attention rows to fit ws: per chunk = CN*128*(512+1536)*2 B
    int CN = 1024;
    while (CN > 64 && (size_t)2097152 + (size_t)CN*524288 > ws_size) CN >>= 1;
    u16* xb  = (u16*)(ws + 2097152);
    u16* QKV = xb + (size_t)CN*128*512;

    k_wconv<<<1024, 256, 0, stream>>>(Wq, Wk, Wv, Wo, Wcat, Wob);
    int nch = 1024 / CN;
    for (int ch = 0; ch < nch; ++ch) {
        int n0 = ch * CN;
        k_xconv<<<CN*32, 256, 0, stream>>>(x, xb, n0);
        k_gemm<512,    12, false><<<CN*12, 256, 0, stream>>>(xb, Wcat, QKV, nullptr, 0, CN);
        k_attn<<<dim3(8, CN), 256, 0, stream>>>(QKV);
        k_gemm<QKV_LD, 4,  true ><<<CN*4,  256, 0, stream>>>(QKV, Wob, d_out, bo, n0, CN);
    }
}

// Round 3
// 626.341 us; speedup vs baseline: 1.0945x; 1.0587x over previous
//
#include <hip/hip_runtime.h>
#include <stdint.h>

// Axial attention (H axis), N=8 H=128 W=128 C=512, GROUPS=8, gp=64.
// Pipeline: wconv -> xconv(bf16+permute) -> QKV GEMM (256^2 8-phase bf16 MFMA) -> attn -> outproj.
// QKV ws layout: [m][1536] bf16, m = (n_local*128 + h); O overwrites Q cols [0,512).

#define QKV_LD 1536

typedef __attribute__((ext_vector_type(4))) float f32x4;
typedef __attribute__((ext_vector_type(8))) short bf16x8;
typedef unsigned short u16;
typedef unsigned int u32;

#define CBAR() asm volatile("" ::: "memory")
#define SBAR() do { CBAR(); __builtin_amdgcn_s_barrier(); CBAR(); } while(0)
#define LGKM0() do { asm volatile("s_waitcnt lgkmcnt(0)" ::: "memory"); __builtin_amdgcn_sched_barrier(0); } while(0)
#define VMC(n) asm volatile("s_waitcnt vmcnt(" #n ")" ::: "memory")

static __device__ __forceinline__ u16 f2bf(float f){
    union { float f; u32 u; } v; v.f = f;
    u32 r = v.u + 0x7fffu + ((v.u >> 16) & 1u);   // RNE
    return (u16)(r >> 16);
}

static __device__ __forceinline__ void gload16(const void* g, void* l){
    __builtin_amdgcn_global_load_lds((const __attribute__((address_space(1))) void*)g,
                                     (__attribute__((address_space(3))) void*)l, 16, 0, 0);
}

// ---------------- weights fp32 -> bf16 ----------------
__global__ void k_wconv(const float* __restrict__ Wq, const float* __restrict__ Wk,
                        const float* __restrict__ Wv, const float* __restrict__ Wo,
                        u16* __restrict__ Wcat, u16* __restrict__ Wob){
    int e = (blockIdx.x * 256 + threadIdx.x) * 4;
    if (e < 1536*512) {
        int row = e >> 9, col = e & 511;
        const float* s = (row < 512) ? (Wq + row*512)
                        : (row < 1024 ? Wk + (row-512)*512 : Wv + (row-1024)*512);
        float4 v = *(const float4*)(s + col);
        ushort4 o = { f2bf(v.x), f2bf(v.y), f2bf(v.z), f2bf(v.w) };
        *(ushort4*)(Wcat + e) = o;
    } else {
        int e2 = e - 1536*512;
        float4 v = *(const float4*)(Wo + e2);
        ushort4 o = { f2bf(v.x), f2bf(v.y), f2bf(v.z), f2bf(v.w) };
        *(ushort4*)(Wob + e2) = o;
    }
}

// ---------------- x fp32 (N,H,W,C) -> xb bf16 [(n0+nl)*128+h][512] ----------------
__global__ void k_xconv(const float* __restrict__ x, u16* __restrict__ xb, int n0){
    int t = blockIdx.x * 256 + threadIdx.x;
    int ml = t >> 6;                 // chunk-local token row
    int c0 = (t & 63) << 3;          // 8 channels per thread
    int nl = ml >> 7, h = ml & 127;
    int n = n0 + nl, nb = n >> 7, w = n & 127;
    const float* src = x + (size_t)((nb*128 + h)*128 + w) * 512 + c0;
    float4 a = *(const float4*)(src);
    float4 b = *(const float4*)(src + 4);
    uint4 o;
    o.x = (u32)f2bf(a.x) | ((u32)f2bf(a.y) << 16);
    o.y = (u32)f2bf(a.z) | ((u32)f2bf(a.w) << 16);
    o.z = (u32)f2bf(b.x) | ((u32)f2bf(b.y) << 16);
    o.w = (u32)f2bf(b.z) | ((u32)f2bf(b.w) << 16);
    *(uint4*)(xb + (size_t)ml*512 + c0) = o;
}

// ---------------- 256x256 8-phase GEMM: C[MxN] = A[MxK=512] * B^T ----------------
// 8 waves (2M x 4N), BK=64, per-wave out 128x64 (acc[8][4] f32x4).
// LDS 128 KiB dynamic: buf{0,1} x slab{A_k0,B_k0,A_k1,B_k1} x 16 KiB ([256 rows][32 kk] bf16).
// Staged via global_load_lds (linear dest) with inverse-swizzled SOURCE; ds_read uses
// slot = (lg ^ ((r>>1)&3))*16 -> 8 distinct 16B positions per 16-lane group (2-way, free).
// Counted vmcnt(4) at q1/q3; one half-tile of tile t+1 issued per phase; never drain in loop.
template<int LDA, int NCOL, bool OUTPROJ>
__global__ __launch_bounds__(512, 2) void k_gemm2(const u16* __restrict__ A, const u16* __restrict__ B,
                                                  void* __restrict__ Cout, const float* __restrict__ bias,
                                                  int n0, int nrow){
    extern __shared__ char smc[];
    const int tid = threadIdx.x;
    const int wid = tid >> 6, lane = tid & 63, lg = lane >> 4, li = lane & 15;
    const int wm = wid >> 2, wn = wid & 3;           // 2 x 4 wave grid
    const int bid = blockIdx.x;
    const int xcd = bid & 7, l = bid >> 3;
    const int row_tile = xcd * (nrow >> 3) + l / NCOL;
    const int col_tile = l % NCOL;
    const int m0 = row_tile * 256, nn0 = col_tile * 256;

    // stage one half-tile ([256 rows][32 kk] slab): 2 gload16 per wave, wave w rows [w*32,w*32+32)
    auto stage = [&](const u16* __restrict__ G, int gbase, int kbase, int ld, char* slab){
        #pragma unroll
        for (int i = 0; i < 2; ++i) {
            int R = wid*32 + i*16;
            int r = R + (lane >> 2);
            int srcq = (lane & 3) ^ ((r >> 1) & 3);
            gload16((const char*)(G + (size_t)(gbase + r)*ld + kbase) + srcq*16,
                    slab + R*64);
        }
    };

    f32x4 acc[8][4];
    #pragma unroll
    for (int i = 0; i < 8; ++i)
        #pragma unroll
        for (int j = 0; j < 4; ++j)
            acc[i][j] = f32x4{0.f, 0.f, 0.f, 0.f};

    // prologue: stage tile 0 (A0,B0,A1,B1), wait oldest 2 half-tiles
    stage(A, m0, 0,  LDA, smc + 0*16384);
    stage(B, nn0, 0, 512, smc + 1*16384);
    stage(A, m0, 32, LDA, smc + 2*16384);
    stage(B, nn0, 32, 512, smc + 3*16384);
    VMC(4);
    SBAR();

    const int nT = 8;   // K = 512
    int cur = 0;
    bf16x8 af[4], bfr[4];

    for (int t = 0; t < nT; ++t) {
        const bool pf = (t + 1 < nT);
        char* bc = smc + cur*65536;
        char* bn = smc + (cur^1)*65536;
        const int kn = (t + 1) * 64;

        // ---- q0: ks=0, mf 0..3 (reads A_k0 + B_k0)
        #pragma unroll
        for (int f = 0; f < 4; ++f) {
            int r = wm*128 + f*16 + li;
            af[f] = *(const bf16x8*)(bc + 0*16384 + r*64 + (((lg ^ (r>>1)) & 3) << 4));
        }
        #pragma unroll
        for (int f = 0; f < 4; ++f) {
            int r = wn*64 + f*16 + li;
            bfr[f] = *(const bf16x8*)(bc + 1*16384 + r*64 + (((lg ^ (r>>1)) & 3) << 4));
        }
        if (pf) stage(A, m0, kn, LDA, bn + 0*16384);
        SBAR(); LGKM0();
        __builtin_amdgcn_s_setprio(1);
        #pragma unroll
        for (int f = 0; f < 4; ++f)
            #pragma unroll
            for (int n = 0; n < 4; ++n)
                acc[f][n] = __builtin_amdgcn_mfma_f32_16x16x32_bf16(af[f], bfr[n], acc[f][n], 0, 0, 0);
        __builtin_amdgcn_s_setprio(0);
        SBAR();

        // ---- q1: ks=0, mf 4..7 (reads A_k0; B in regs)
        #pragma unroll
        for (int f = 0; f < 4; ++f) {
            int r = wm*128 + (4+f)*16 + li;
            af[f] = *(const bf16x8*)(bc + 0*16384 + r*64 + (((lg ^ (r>>1)) & 3) << 4));
        }
        if (pf) stage(B, nn0, kn, 512, bn + 1*16384);
        if (pf) { VMC(4); } else { VMC(0); }   // need t.A_k1, t.B_k1 after next barrier
        SBAR(); LGKM0();
        __builtin_amdgcn_s_setprio(1);
        #pragma unroll
        for (int f = 0; f < 4; ++f)
            #pragma unroll
            for (int n = 0; n < 4; ++n)
                acc[4+f][n] = __builtin_amdgcn_mfma_f32_16x16x32_bf16(af[f], bfr[n], acc[4+f][n], 0, 0, 0);
        __builtin_amdgcn_s_setprio(0);
        SBAR();

        // ---- q2: ks=1, mf 0..3 (reads A_k1 + B_k1)
        #pragma unroll
        for (int f = 0; f < 4; ++f) {
            int r = wm*128 + f*16 + li;
            af[f] = *(const bf16x8*)(bc + 2*16384 + r*64 + (((lg ^ (r>>1)) & 3) << 4));
        }
        #pragma unroll
        for (int f = 0; f < 4; ++f) {
            int r = wn*64 + f*16 + li;
            bfr[f] = *(const bf16x8*)(bc + 3*16384 + r*64 + (((lg ^ (r>>1)) & 3) << 4));
        }
        if (pf) stage(A, m0, kn + 32, LDA, bn + 2*16384);
        SBAR(); LGKM0();
        __builtin_amdgcn_s_setprio(1);
        #pragma unroll
        for (int f = 0; f < 4; ++f)
            #pragma unroll
            for (int n = 0; n < 4; ++n)
                acc[f][n] = __builtin_amdgcn_mfma_f32_16x16x32_bf16(af[f], bfr[n], acc[f][n], 0, 0, 0);
        __builtin_amdgcn_s_setprio(0);
        SBAR();

        // ---- q3: ks=1, mf 4..7 (reads A_k1)
        #pragma unroll
        for (int f = 0; f < 4; ++f) {
            int r = wm*128 + (4+f)*16 + li;
            af[f] = *(const bf16x8*)(bc + 2*16384 + r*64 + (((lg ^ (r>>1)) & 3) << 4));
        }
        if (pf) stage(B, nn0, kn + 32, 512, bn + 3*16384);
        if (pf) { VMC(4); }                    // need t+1.A_k0, t+1.B_k0 after next barrier
        SBAR(); LGKM0();
        __builtin_amdgcn_s_setprio(1);
        #pragma unroll
        for (int f = 0; f < 4; ++f)
            #pragma unroll
            for (int n = 0; n < 4; ++n)
                acc[4+f][n] = __builtin_amdgcn_mfma_f32_16x16x32_bf16(af[f], bfr[n], acc[4+f][n], 0, 0, 0);
        __builtin_amdgcn_s_setprio(0);
        SBAR();

        cur ^= 1;
    }

    // epilogue
    if (!OUTPROJ) {
        u16* C = (u16*)Cout;
        #pragma unroll
        for (int mf = 0; mf < 8; ++mf)
            #pragma unroll
            for (int nf = 0; nf < 4; ++nf)
                #pragma unroll
                for (int r = 0; r < 4; ++r) {
                    int row = m0 + wm*128 + mf*16 + lg*4 + r;
                    int col = nn0 + wn*64 + nf*16 + li;
                    C[(size_t)row*QKV_LD + col] = f2bf(acc[mf][nf][r]);
                }
    } else {
        float* C = (float*)Cout;
        #pragma unroll
        for (int mf = 0; mf < 8; ++mf)
            #pragma unroll
            for (int nf = 0; nf < 4; ++nf)
                #pragma unroll
                for (int r = 0; r < 4; ++r) {
                    int row = m0 + wm*128 + mf*16 + lg*4 + r;   // chunk-local token
                    int col = nn0 + wn*64 + nf*16 + li;
                    int mg = n0*128 + row;
                    int n = mg >> 7, ii = mg & 127;             // n = nb*128+w, ii = h
                    int nb = n >> 7, w = n & 127;
                    C[(size_t)((nb*128 + ii)*128 + w) * 512 + col] = acc[mf][nf][r] + bias[col];
                }
    }
}

// ---------------- attention: one block per (n_local, group), 4 waves x 32 rows ----------------
__global__ __launch_bounds__(256, 2) void k_attn(u16* __restrict__ QKV){
    // LDS: [0,16K) Qs swz, [16K,32K) Ks swz; P overlays [0,34816) after S-phase;
    //      Vt [34816, 34816+17408): [c=64][stride 272B] bf16
    __shared__ char sm[52224];
    const int g = blockIdx.x;
    const int nl = blockIdx.y;
    const int tid = threadIdx.x;
    const int wid = tid >> 6, lane = tid & 63, lg = lane >> 4, li = lane & 15;

    u16* Qg = QKV + (size_t)nl*128*QKV_LD + g*64;   // K at +512, V at +1024

    #pragma unroll
    for (int it = 0; it < 4; ++it) {
        int gi = it*256 + tid;
        int row = gi >> 3, gs = gi & 7;
        int sw = (gs ^ (row & 7)) << 4;
        gload16((const char*)(Qg + (size_t)row*QKV_LD) + sw,        sm + it*4096 + wid*1024);
        gload16((const char*)(Qg + 512 + (size_t)row*QKV_LD) + sw,  sm + 16384 + it*4096 + wid*1024);
    }
    {   // V transposed: Vt[c][j] — vectorized global loads, scalar LDS scatter
        int j = tid & 127, ch = tid >> 7;
        const u16* src = Qg + 1024 + (size_t)j*QKV_LD + ch*32;
        uint4 a0 = *(const uint4*)(src);
        uint4 a1 = *(const uint4*)(src + 8);
        uint4 a2 = *(const uint4*)(src + 16);
        uint4 a3 = *(const uint4*)(src + 24);
        u32 w[16] = {a0.x,a0.y,a0.z,a0.w, a1.x,a1.y,a1.z,a1.w,
                     a2.x,a2.y,a2.z,a2.w, a3.x,a3.y,a3.z,a3.w};
        char* dst = sm + 34816 + ch*32*272 + j*2;
        #pragma unroll
        for (int cc = 0; cc < 32; ++cc) {
            u32 word = w[cc >> 1];
            u16 val = (cc & 1) ? (u16)(word >> 16) : (u16)(word & 0xffffu);
            *(u16*)(dst + cc*272) = val;
        }
    }
    __syncthreads();

    const int i0w = wid*32;
    f32x4 s[2][8];
    #pragma unroll
    for (int t = 0; t < 2; ++t)
        #pragma unroll
        for (int tj = 0; tj < 8; ++tj)
            s[t][tj] = f32x4{0.f,0.f,0.f,0.f};

    #pragma unroll
    for (int ks = 0; ks < 2; ++ks) {
        bf16x8 qf[2];
        #pragma unroll
        for (int t = 0; t < 2; ++t) {
            int ra = i0w + t*16 + li;
            qf[t] = *(const bf16x8*)(sm + ra*128 + ((ks*64 + lg*16) ^ ((ra & 7) << 4)));
        }
        #pragma unroll
        for (int tj = 0; tj < 8; ++tj) {
            int rb = tj*16 + li;
            bf16x8 kf = *(const bf16x8*)(sm + 16384 + rb*128 + ((ks*64 + lg*16) ^ ((rb & 7) << 4)));
            #pragma unroll
            for (int t = 0; t < 2; ++t)
                s[t][tj] = __builtin_amdgcn_mfma_f32_16x16x32_bf16(qf[t], kf, s[t][tj], 0, 0, 0);
        }
    }
    __syncthreads();   // Q/K LDS dead -> P overlay is now safe

    // wave-parallel softmax over j (scale 1/8 folded into exp arg)
    char* pb = sm + wid*8704;     // per-wave P [32 rows][272B stride]
    #pragma unroll
    for (int t = 0; t < 2; ++t) {
        #pragma unroll
        for (int r = 0; r < 4; ++r) {
            float mx = -1e30f;
            #pragma unroll
            for (int tj = 0; tj < 8; ++tj) mx = fmaxf(mx, s[t][tj][r]);
            #pragma unroll
            for (int off = 1; off < 16; off <<= 1) mx = fmaxf(mx, __shfl_xor(mx, off, 64));
            float p[8]; float sum = 0.f;
            #pragma unroll
            for (int tj = 0; tj < 8; ++tj) { p[tj] = __expf((s[t][tj][r] - mx)*0.125f); sum += p[tj]; }
            #pragma unroll
            for (int off = 1; off < 16; off <<= 1) sum += __shfl_xor(sum, off, 64);
            float inv = 1.0f / sum;
            int prow = t*16 + lg*4 + r;
            #pragma unroll
            for (int tj = 0; tj < 8; ++tj)
                *(u16*)(pb + prow*272 + (tj*16 + li)*2) = f2bf(p[tj]*inv);
        }
    }

    // O = P @ V
    f32x4 o[2][4];
    #pragma unroll
    for (int t = 0; t < 2; ++t)
        #pragma unroll
        for (int tc = 0; tc < 4; ++tc)
            o[t][tc] = f32x4{0.f,0.f,0.f,0.f};

    #pragma unroll
    for (int ks = 0; ks < 4; ++ks) {
        bf16x8 pf[2];
        #pragma unroll
        for (int t = 0; t < 2; ++t)
            pf[t] = *(const bf16x8*)(pb + (t*16 + li)*272 + (ks*64 + lg*16));
        #pragma unroll
        for (int tc = 0; tc < 4; ++tc) {
            bf16x8 vf = *(const bf16x8*)(sm + 34816 + (tc*16 + li)*272 + (ks*64 + lg*16));
            #pragma unroll
            for (int t = 0; t < 2; ++t)
                o[t][tc] = __builtin_amdgcn_mfma_f32_16x16x32_bf16(pf[t], vf, o[t][tc], 0, 0, 0);
        }
    }

    // O overwrites this block's Q slice (consumed into LDS at block start)
    #pragma unroll
    for (int t = 0; t < 2; ++t)
        #pragma unroll
        for (int tc = 0; tc < 4; ++tc)
            #pragma unroll
            for (int r = 0; r < 4; ++r) {
                int irow = i0w + t*16 + lg*4 + r;
                int col = tc*16 + li;
                Qg[(size_t)irow*QKV_LD + col] = f2bf(o[t][tc][r]);
            }
}

extern "C" void kernel_launch(void* const* d_in, const int* in_sizes, int n_in,
                              void* d_out, int out_size, void* d_ws, size_t ws_size,
                              hipStream_t stream){
    const float* x  = (const float*)d_in[0];
    const float* Wq = (const float*)d_in[1];
    const float* Wk = (const float*)d_in[2];
    const float* Wv = (const float*)d_in[3];
    const float* Wo = (const float*)d_in[4];
    const float* bo = (const float*)d_in[5];

    char* ws = (char*)d_ws;
    u16* Wcat = (u16*)ws;               // 1536*512 bf16
    u16* Wob  = Wcat + 1536*512;        // 512*512 bf16 ; weights end at 2097152 B

    // chunk over the 1024 attention rows to fit ws: per chunk = CN*128*(512+1536)*2 B
    int CN = 1024;
    while (CN > 64 && (size_t)2097152 + (size_t)CN*524288 > ws_size) CN >>= 1;
    u16* xb  = (u16*)(ws + 2097152);
    u16* QKV = xb + (size_t)CN*128*512;

    // 128 KiB dynamic LDS for the 8-phase GEMMs (idempotent; not a stream op, capture-safe)
    hipFuncSetAttribute((const void*)&k_gemm2<512, 6, false>,
                        hipFuncAttributeMaxDynamicSharedMemorySize, 131072);
    hipFuncSetAttribute((const void*)&k_gemm2<QKV_LD, 2, true>,
                        hipFuncAttributeMaxDynamicSharedMemorySize, 131072);

    k_wconv<<<1024, 256, 0, stream>>>(Wq, Wk, Wv, Wo, Wcat, Wob);
    int nch = 1024 / CN;
    for (int ch = 0; ch < nch; ++ch) {
        int n0 = ch * CN;
        int nrow = (CN * 128) / 256;    // 256-row tiles in this chunk (divisible by 8 for CN>=16)
        k_xconv<<<CN*32, 256, 0, stream>>>(x, xb, n0);
        k_gemm2<512,    6, false><<<nrow*6, 512, 131072, stream>>>(xb, Wcat, QKV, nullptr, 0, nrow);
        k_attn<<<dim3(8, CN), 256, 0, stream>>>(QKV);
        k_gemm2<QKV_LD, 2, true ><<<nrow*2, 512, 131072, stream>>>(QKV, Wob, d_out, bo, n0, nrow);
    }
}